// Round 7
// baseline (373.008 us; speedup 1.0000x reference)
//
#include <hip/hip_runtime.h>

typedef unsigned short u16;
typedef unsigned int u32;
typedef __bf16 bf16x8 __attribute__((ext_vector_type(8)));
typedef __bf16 bf16x4 __attribute__((ext_vector_type(4)));
typedef short s16x4 __attribute__((ext_vector_type(4)));
typedef float f32x4 __attribute__((ext_vector_type(4)));

struct __align__(8) u16x4 { u16 x, y, z, w; };

__device__ __forceinline__ void async_copy16(const void* g, void* l) {
  __builtin_amdgcn_global_load_lds(
      (__attribute__((address_space(1))) void*)g,
      (__attribute__((address_space(3))) void*)l, 16, 0, 0);
}

__device__ __forceinline__ u16 f2bf(float f) {
  unsigned u = __builtin_bit_cast(unsigned, f);
  u = (u + 0x7FFFu + ((u >> 16) & 1u)) >> 16;
  return (u16)u;
}
__device__ __forceinline__ float bf2f(u16 h) {
  unsigned u = ((unsigned)h) << 16;
  return __builtin_bit_cast(float, u);
}

// NOTE: call amdgcn builtins DIRECTLY — host pass parses aux-target builtins,
// but __has_builtin() is false for them on host (round-3 compile failure).
__device__ __forceinline__ float fast_exp2(float x) {
  return __builtin_amdgcn_exp2f(x);
}
__device__ __forceinline__ float fast_rcp(float x) {
  return __builtin_amdgcn_rcpf(x);
}

// 16x16x16 bf16 MFMA (legacy shape, v4i16 operands; k = quad*4 + j)
__device__ __forceinline__ f32x4 mfma16(bf16x4 a, bf16x4 b, f32x4 c) {
  return __builtin_amdgcn_mfma_f32_16x16x16bf16_1k(
      __builtin_bit_cast(s16x4, a), __builtin_bit_cast(s16x4, b), c, 0, 0, 0);
}

// SCALE * log2(e), folded into Q at the gemm1 epilogue.
#define CEXP 0.18033688011112042f

// ---------------------------------------------------------------------------
// Mode detection (bf16 vs fp32 inputs) — see round-1 notes. flag=0 -> fp32.
// ---------------------------------------------------------------------------
__global__ void detect_mode(const u32* __restrict__ probe, int* __restrict__ flag) {
  __shared__ int cnt[256];
  int t = threadIdx.x;
  int c = 0;
#pragma unroll
  for (int j = 0; j < 16; ++j) {
    u32 v = probe[t + j * 256];
    unsigned e = (v >> 7) & 0xFFu;
    c += (e >= 100u && e <= 130u) ? 1 : 0;
  }
  cnt[t] = c;
  __syncthreads();
  for (int s = 128; s > 0; s >>= 1) {
    if (t < s) cnt[t] += cnt[t + s];
    __syncthreads();
  }
  if (t == 0) *flag = (cnt[0] * 2 > 4096) ? 1 : 0;
}

__global__ void convert_in(const void* __restrict__ src, u16* __restrict__ dst,
                           const int* __restrict__ flag, int n) {
  int mode = *flag;
  int i = (blockIdx.x * blockDim.x + threadIdx.x) * 8;
  if (i >= n) return;
  if (mode == 1) {
    *(uint4*)(dst + i) = *(const uint4*)((const u16*)src + i);
  } else {
    const float* s = (const float*)src;
    float4 a = *(const float4*)(s + i);
    float4 b = *(const float4*)(s + i + 4);
    uint4 o;
    o.x = (u32)f2bf(a.x) | ((u32)f2bf(a.y) << 16);
    o.y = (u32)f2bf(a.z) | ((u32)f2bf(a.w) << 16);
    o.z = (u32)f2bf(b.x) | ((u32)f2bf(b.y) << 16);
    o.w = (u32)f2bf(b.z) | ((u32)f2bf(b.w) << 16);
    *(uint4*)(dst + i) = o;
  }
}

// ---------------------------------------------------------------------------
// NT GEMM: 128x128 tile, BK=64, DOUBLE-BUFFERED staging.
// Round-6 counters (single-buffered): MfmaUtil 16.6%, VALUBusy 9.6%, HBM 13%
// -> latency-bound: 2-barrier K-loop exposed full global->LDS latency x16
// iters (K=1024 too small to amortize). Now: prologue prefetch tile0; each
// iter one barrier (drains prefetch issued a full compute-phase earlier),
// issue tile k+1 into other buffer, compute tile k. Same safety argument as
// attn_fwd dbuf. LDS 2*(16K+16K) = 64 KB -> 2 blocks/CU.
// QKV mode (vT != nullptr): cols<1024 (Q) scaled by CEXP; cols>=2048 (V)
// stored transposed per head to vT.
// ---------------------------------------------------------------------------
__global__ __launch_bounds__(256, 2) void gemm_bt(
    const u16* __restrict__ A, const u16* __restrict__ Bm,
    u16* __restrict__ C, u16* __restrict__ vT, const u16* __restrict__ bias,
    float* __restrict__ outF, const int* __restrict__ flagp,
    int K, int ldc)
{
  __shared__ __align__(16) u16 As[2][8][128][8];
  __shared__ __align__(16) u16 Bs[2][8][128][8];

  const int t = threadIdx.x;
  const int lane = t & 63, wave = t >> 6;
  const int quad = lane >> 4, l16 = lane & 15;
  const int wm = wave & 1, wn = wave >> 1;
  const int rowbase = blockIdx.y * 128;
  const int colbase = blockIdx.x * 128;

  f32x4 acc[4][4] = {};

  const u16* Ag[4]; const u16* Bg[4]; unsigned ldsoff[4];
#pragma unroll
  for (int q = 0; q < 4; ++q) {
    int s = q * 256 + t;
    int row = s & 127, c = s >> 7;
    Ag[q] = A + (size_t)(rowbase + row) * K + c * 8;
    Bg[q] = Bm + (size_t)(colbase + row) * K + c * 8;
    ldsoff[q] = (unsigned)(s & ~63) * 8;
  }

  const int nkb = K >> 6;
  // prologue: prefetch k-tile 0 into buffer 0
#pragma unroll
  for (int q = 0; q < 4; ++q) {
    async_copy16(Ag[q], (u16*)As + ldsoff[q]);
    async_copy16(Bg[q], (u16*)Bs + ldsoff[q]);
  }

  for (int kb = 0; kb < nkb; ++kb) {
    const int cur = kb & 1, nxt = cur ^ 1;
    __syncthreads();   // drains prefetch of buf[cur]; compute(kb-1) joined
    if (kb + 1 < nkb) {
      const int k1 = (kb + 1) << 6;
#pragma unroll
      for (int q = 0; q < 4; ++q) {
        async_copy16(Ag[q] + k1, (u16*)As + (unsigned)nxt * 8192 + ldsoff[q]);
        async_copy16(Bg[q] + k1, (u16*)Bs + (unsigned)nxt * 8192 + ldsoff[q]);
      }
    }
#pragma unroll
    for (int ks = 0; ks < 2; ++ks) {
      bf16x8 af[4], bfr[4];
#pragma unroll
      for (int i = 0; i < 4; ++i)
        af[i] = *(const bf16x8*)&As[cur][ks * 4 + quad][wm * 64 + i * 16 + l16][0];
#pragma unroll
      for (int j = 0; j < 4; ++j)
        bfr[j] = *(const bf16x8*)&Bs[cur][ks * 4 + quad][wn * 64 + j * 16 + l16][0];
#pragma unroll
      for (int i = 0; i < 4; ++i)
#pragma unroll
        for (int j = 0; j < 4; ++j)
          acc[i][j] = __builtin_amdgcn_mfma_f32_16x16x32_bf16(af[i], bfr[j], acc[i][j], 0, 0, 0);
    }
  }

  if (vT != nullptr && colbase >= 2048) {
#pragma unroll
    for (int i = 0; i < 4; ++i) {
      int rg = rowbase + wm * 64 + i * 16 + quad * 4;
      int b = rg >> 11, n = rg & 2047;
#pragma unroll
      for (int j = 0; j < 4; ++j) {
        int cg = colbase + wn * 64 + j * 16 + l16;
        size_t idx = ((size_t)(b * 1024 + (cg - 2048))) * 2048 + n;
        u16x4 pk;
        pk.x = f2bf(acc[i][j][0]); pk.y = f2bf(acc[i][j][1]);
        pk.z = f2bf(acc[i][j][2]); pk.w = f2bf(acc[i][j][3]);
        *(u16x4*)(vT + idx) = pk;
      }
    }
  } else {
    const bool f32out = (flagp != nullptr) && (*flagp == 0);
    // Q-section scaling: fold SCALE*log2e into Q so attn's P = exp2(s) direct.
    const float scl = (vT != nullptr && colbase < 1024) ? CEXP : 1.0f;
#pragma unroll
    for (int j = 0; j < 4; ++j) {
      int cg = colbase + wn * 64 + j * 16 + l16;
      float bv = bias ? bf2f(bias[cg]) : 0.0f;
#pragma unroll
      for (int i = 0; i < 4; ++i) {
#pragma unroll
        for (int r = 0; r < 4; ++r) {
          int rg = rowbase + wm * 64 + i * 16 + quad * 4 + r;
          float val = acc[i][j][r] * scl + bv;
          if (f32out) outF[(size_t)rg * ldc + cg] = val;
          else        C[(size_t)rg * ldc + cg] = f2bf(val);
        }
      }
    }
  }
}

// ---------------------------------------------------------------------------
// Flash attention (unchanged from round 6): transpose-free P path, TK=64
// double-buffered, 4 blocks/CU, static softmax, Q pre-scaled by CEXP.
// ---------------------------------------------------------------------------
__global__ __launch_bounds__(256, 4) void attn_fwd(
    const u16* __restrict__ qk, const u16* __restrict__ vT, u16* __restrict__ outp)
{
  __shared__ __align__(16) u16 Ks[2][8][64][8];   // [buf][hd-chunk][key][8]
  __shared__ __align__(16) u16 Vs[2][8][64][8];   // [buf][key-chunk][e][8]

  const int t = threadIdx.x;
  const int lane = t & 63, wave = t >> 6;
  const int quad = lane >> 4, l16 = lane & 15;
  const int bh = blockIdx.x, b = bh >> 4, h = bh & 15;
  const int qtile = blockIdx.y;
  const size_t row0 = (size_t)b * 2048;

  bf16x8 qf[2][2];
  {
    const u16* qp = qk + (row0 + qtile * 128 + wave * 32 + l16) * 2048
                    + h * 64 + quad * 8;
#pragma unroll
    for (int i = 0; i < 2; ++i)
#pragma unroll
      for (int ks = 0; ks < 2; ++ks)
        qf[i][ks] = *(const bf16x8*)(qp + i * 16 * 2048 + ks * 32);
  }

  const u16* Kg[2]; const u16* Vg[2]; unsigned off2[2];
#pragma unroll
  for (int q = 0; q < 2; ++q) {
    int s = q * 256 + t;
    int row = s & 63, c = s >> 6;
    Kg[q] = qk + (row0 + row) * 2048 + (1024 + h * 64 + c * 8);
    Vg[q] = vT + (size_t)(b * 1024 + h * 64 + row) * 2048 + c * 8;
    off2[q] = (unsigned)(s & ~63) * 8;
  }

#pragma unroll
  for (int q = 0; q < 2; ++q) {
    async_copy16(Kg[q], (u16*)Ks + off2[q]);
    async_copy16(Vg[q], (u16*)Vs + off2[q]);
  }

  f32x4 o[2][4] = {};
  float l_r[2] = {0.0f, 0.0f};

  for (int kb = 0; kb < 32; ++kb) {
    const int cur = kb & 1, nxt = cur ^ 1;
    __syncthreads();
    if (kb < 31) {
#pragma unroll
      for (int q = 0; q < 2; ++q) {
        async_copy16(Kg[q] + (size_t)(kb + 1) * 64 * 2048,
                     (u16*)Ks + (unsigned)nxt * 4096 + off2[q]);
        async_copy16(Vg[q] + (kb + 1) * 64,
                     (u16*)Vs + (unsigned)nxt * 4096 + off2[q]);
      }
    }

    f32x4 sc[2][4] = {};
#pragma unroll
    for (int ks = 0; ks < 2; ++ks) {
#pragma unroll
      for (int j = 0; j < 4; ++j) {
        bf16x8 kf = *(const bf16x8*)&Ks[cur][ks * 4 + quad][j * 16 + l16][0];
#pragma unroll
        for (int i = 0; i < 2; ++i)
          sc[i][j] = __builtin_amdgcn_mfma_f32_16x16x32_bf16(kf, qf[i][ks], sc[i][j], 0, 0, 0);
      }
    }

#pragma unroll
    for (int jc = 0; jc < 4; ++jc) {
      bf16x4 vf[4];
#pragma unroll
      for (int et = 0; et < 4; ++et)
        vf[et] = *(const bf16x4*)&Vs[cur][jc * 2 + (quad >> 1)][et * 16 + l16][(quad & 1) * 4];
      bf16x4 pk[2];
#pragma unroll
      for (int i = 0; i < 2; ++i) {
        f32x4 pv;
#pragma unroll
        for (int r = 0; r < 4; ++r) {
          float p = fast_exp2(sc[i][jc][r]);
          pv[r] = p;
          l_r[i] += p;
        }
        pk[i] = __builtin_convertvector(pv, bf16x4);
      }
#pragma unroll
      for (int i = 0; i < 2; ++i)
#pragma unroll
        for (int et = 0; et < 4; ++et)
          o[i][et] = mfma16(pk[i], vf[et], o[i][et]);
    }
  }

#pragma unroll
  for (int i = 0; i < 2; ++i) {
    l_r[i] += __shfl_xor(l_r[i], 16, 64);
    l_r[i] += __shfl_xor(l_r[i], 32, 64);
    l_r[i] = fast_rcp(l_r[i]);
  }
#pragma unroll
  for (int i = 0; i < 2; ++i)
#pragma unroll
    for (int r = 0; r < 4; ++r) {
      float inv = __shfl(l_r[i], ((lane & 48) >> 2) + r, 64);
      int n = qtile * 128 + wave * 32 + i * 16 + quad * 4 + r;
      size_t base = (row0 + n) * 1024 + h * 64;
#pragma unroll
      for (int et = 0; et < 4; ++et)
        outp[base + et * 16 + l16] = f2bf(o[i][et][r] * inv);
    }
}

// ---------------------------------------------------------------------------
// Workspace (u16 elems): qkbuf 16777216 | vT 8388608 | xb/attn 8388608 |
// wqkvb 3145728 | flag. wprojb/bprojb alias vT after attn_fwd.
// ---------------------------------------------------------------------------
extern "C" void kernel_launch(void* const* d_in, const int* in_sizes, int n_in,
                              void* d_out, int out_size, void* d_ws, size_t ws_size,
                              hipStream_t stream) {
  (void)in_sizes; (void)n_in; (void)out_size; (void)ws_size;
  const void* x_in     = d_in[0];
  const void* wqkv_in  = d_in[1];
  const void* wproj_in = d_in[2];
  const void* bproj_in = d_in[3];

  u16* qkbuf  = (u16*)d_ws;
  u16* vT     = qkbuf + 16777216;
  u16* xb     = vT + 8388608;
  u16* wqkvb  = xb + 8388608;
  int* flag   = (int*)(wqkvb + 3145728);
  u16* attn   = xb;
  u16* wprojb = vT;
  u16* bprojb = vT + 1048576;

  detect_mode<<<1, 256, 0, stream>>>((const u32*)wqkv_in, flag);
  convert_in<<<4096, 256, 0, stream>>>(x_in, xb, flag, 8388608);
  convert_in<<<1536, 256, 0, stream>>>(wqkv_in, wqkvb, flag, 3145728);

  gemm_bt<<<dim3(24, 64), 256, 0, stream>>>(xb, wqkvb, qkbuf, vT, nullptr,
                                            nullptr, nullptr, 1024, 2048);
  attn_fwd<<<dim3(64, 16), 256, 0, stream>>>(qkbuf, vT, attn);

  convert_in<<<512, 256, 0, stream>>>(wproj_in, wprojb, flag, 1048576);
  convert_in<<<1, 256, 0, stream>>>(bproj_in, bprojb, flag, 1024);

  gemm_bt<<<dim3(8, 64), 256, 0, stream>>>(attn, wprojb, (u16*)d_out, nullptr,
                                           bprojb, (float*)d_out, flag, 1024, 1024);
}

// Round 8
// 360.231 us; speedup vs baseline: 1.0355x; 1.0355x over previous
//
#include <hip/hip_runtime.h>

typedef unsigned short u16;
typedef unsigned int u32;
typedef __bf16 bf16x8 __attribute__((ext_vector_type(8)));
typedef __bf16 bf16x4 __attribute__((ext_vector_type(4)));
typedef short s16x4 __attribute__((ext_vector_type(4)));
typedef float f32x4 __attribute__((ext_vector_type(4)));

struct __align__(8) u16x4 { u16 x, y, z, w; };

__device__ __forceinline__ void async_copy16(const void* g, void* l) {
  __builtin_amdgcn_global_load_lds(
      (__attribute__((address_space(1))) void*)g,
      (__attribute__((address_space(3))) void*)l, 16, 0, 0);
}

__device__ __forceinline__ u16 f2bf(float f) {
  unsigned u = __builtin_bit_cast(unsigned, f);
  u = (u + 0x7FFFu + ((u >> 16) & 1u)) >> 16;
  return (u16)u;
}
__device__ __forceinline__ float bf2f(u16 h) {
  unsigned u = ((unsigned)h) << 16;
  return __builtin_bit_cast(float, u);
}

// NOTE: call amdgcn builtins DIRECTLY — host pass parses aux-target builtins,
// but __has_builtin() is false for them on host (round-3 compile failure).
__device__ __forceinline__ float fast_exp2(float x) {
  return __builtin_amdgcn_exp2f(x);
}
__device__ __forceinline__ float fast_rcp(float x) {
  return __builtin_amdgcn_rcpf(x);
}

// 16x16x16 bf16 MFMA (legacy shape, v4i16 operands; k = quad*4 + j)
__device__ __forceinline__ f32x4 mfma16(bf16x4 a, bf16x4 b, f32x4 c) {
  return __builtin_amdgcn_mfma_f32_16x16x16bf16_1k(
      __builtin_bit_cast(s16x4, a), __builtin_bit_cast(s16x4, b), c, 0, 0, 0);
}

// SCALE * log2(e), folded into Q at the gemm1 epilogue.
#define CEXP 0.18033688011112042f

// ---------------------------------------------------------------------------
// Mode detection (bf16 vs fp32 inputs) — see round-1 notes. flag=0 -> fp32.
// ---------------------------------------------------------------------------
__global__ void detect_mode(const u32* __restrict__ probe, int* __restrict__ flag) {
  __shared__ int cnt[256];
  int t = threadIdx.x;
  int c = 0;
#pragma unroll
  for (int j = 0; j < 16; ++j) {
    u32 v = probe[t + j * 256];
    unsigned e = (v >> 7) & 0xFFu;
    c += (e >= 100u && e <= 130u) ? 1 : 0;
  }
  cnt[t] = c;
  __syncthreads();
  for (int s = 128; s > 0; s >>= 1) {
    if (t < s) cnt[t] += cnt[t + s];
    __syncthreads();
  }
  if (t == 0) *flag = (cnt[0] * 2 > 4096) ? 1 : 0;
}

__global__ void convert_in(const void* __restrict__ src, u16* __restrict__ dst,
                           const int* __restrict__ flag, int n) {
  int mode = *flag;
  int i = (blockIdx.x * blockDim.x + threadIdx.x) * 8;
  if (i >= n) return;
  if (mode == 1) {
    *(uint4*)(dst + i) = *(const uint4*)((const u16*)src + i);
  } else {
    const float* s = (const float*)src;
    float4 a = *(const float4*)(s + i);
    float4 b = *(const float4*)(s + i + 4);
    uint4 o;
    o.x = (u32)f2bf(a.x) | ((u32)f2bf(a.y) << 16);
    o.y = (u32)f2bf(a.z) | ((u32)f2bf(a.w) << 16);
    o.z = (u32)f2bf(b.x) | ((u32)f2bf(b.y) << 16);
    o.w = (u32)f2bf(b.z) | ((u32)f2bf(b.w) << 16);
    *(uint4*)(dst + i) = o;
  }
}

// ---------------------------------------------------------------------------
// NT GEMM: 128x128 tile, BK=32, double-buffered, 4 blocks/CU.
// Round-7 post-mortem: dbuf at 64KB LDS (2 blocks/CU) was NEUTRAL vs
// single-buf at 32KB (3 blocks/CU) — co-residency, not pipelining, is the
// lever in this latency-bound regime (m99/m100 lesson). So: halve the tile
// depth (BK=32 -> 32KB total WITH dbuf) and run 4 blocks/CU, mirroring the
// attn_fwd structure that measured well (round 6).
// QKV mode (vT != nullptr): cols<1024 (Q) scaled by CEXP; cols>=2048 (V)
// stored transposed per head to vT.
// ---------------------------------------------------------------------------
__global__ __launch_bounds__(256, 4) void gemm_bt(
    const u16* __restrict__ A, const u16* __restrict__ Bm,
    u16* __restrict__ C, u16* __restrict__ vT, const u16* __restrict__ bias,
    float* __restrict__ outF, const int* __restrict__ flagp,
    int K, int ldc)
{
  __shared__ __align__(16) u16 As[2][4][128][8];   // [buf][k-chunk][row][8]
  __shared__ __align__(16) u16 Bs[2][4][128][8];

  const int t = threadIdx.x;
  const int lane = t & 63, wave = t >> 6;
  const int quad = lane >> 4, l16 = lane & 15;
  const int wm = wave & 1, wn = wave >> 1;
  const int rowbase = blockIdx.y * 128;
  const int colbase = blockIdx.x * 128;

  f32x4 acc[4][4] = {};

  const u16* Ag[2]; const u16* Bg[2]; unsigned ldsoff[2];
#pragma unroll
  for (int q = 0; q < 2; ++q) {
    int s = q * 256 + t;
    int row = s & 127, c = s >> 7;           // c in [0,4)
    Ag[q] = A + (size_t)(rowbase + row) * K + c * 8;
    Bg[q] = Bm + (size_t)(colbase + row) * K + c * 8;
    ldsoff[q] = (unsigned)(s & ~63) * 8;
  }

  const int nkb = K >> 5;
  // prologue: prefetch k-tile 0 into buffer 0
#pragma unroll
  for (int q = 0; q < 2; ++q) {
    async_copy16(Ag[q], (u16*)As + ldsoff[q]);
    async_copy16(Bg[q], (u16*)Bs + ldsoff[q]);
  }

  for (int kb = 0; kb < nkb; ++kb) {
    const int cur = kb & 1, nxt = cur ^ 1;
    __syncthreads();   // drains prefetch of buf[cur]; compute(kb-1) joined
    if (kb + 1 < nkb) {
      const int k1 = (kb + 1) << 5;
#pragma unroll
      for (int q = 0; q < 2; ++q) {
        async_copy16(Ag[q] + k1, (u16*)As + (unsigned)nxt * 4096 + ldsoff[q]);
        async_copy16(Bg[q] + k1, (u16*)Bs + (unsigned)nxt * 4096 + ldsoff[q]);
      }
    }
    bf16x8 af[4], bfr[4];
#pragma unroll
    for (int i = 0; i < 4; ++i)
      af[i] = *(const bf16x8*)&As[cur][quad][wm * 64 + i * 16 + l16][0];
#pragma unroll
    for (int j = 0; j < 4; ++j)
      bfr[j] = *(const bf16x8*)&Bs[cur][quad][wn * 64 + j * 16 + l16][0];
#pragma unroll
    for (int i = 0; i < 4; ++i)
#pragma unroll
      for (int j = 0; j < 4; ++j)
        acc[i][j] = __builtin_amdgcn_mfma_f32_16x16x32_bf16(af[i], bfr[j], acc[i][j], 0, 0, 0);
  }

  if (vT != nullptr && colbase >= 2048) {
#pragma unroll
    for (int i = 0; i < 4; ++i) {
      int rg = rowbase + wm * 64 + i * 16 + quad * 4;
      int b = rg >> 11, n = rg & 2047;
#pragma unroll
      for (int j = 0; j < 4; ++j) {
        int cg = colbase + wn * 64 + j * 16 + l16;
        size_t idx = ((size_t)(b * 1024 + (cg - 2048))) * 2048 + n;
        u16x4 pk;
        pk.x = f2bf(acc[i][j][0]); pk.y = f2bf(acc[i][j][1]);
        pk.z = f2bf(acc[i][j][2]); pk.w = f2bf(acc[i][j][3]);
        *(u16x4*)(vT + idx) = pk;
      }
    }
  } else {
    const bool f32out = (flagp != nullptr) && (*flagp == 0);
    // Q-section scaling: fold SCALE*log2e into Q so attn's P = exp2(s) direct.
    const float scl = (vT != nullptr && colbase < 1024) ? CEXP : 1.0f;
#pragma unroll
    for (int j = 0; j < 4; ++j) {
      int cg = colbase + wn * 64 + j * 16 + l16;
      float bv = bias ? bf2f(bias[cg]) : 0.0f;
#pragma unroll
      for (int i = 0; i < 4; ++i) {
#pragma unroll
        for (int r = 0; r < 4; ++r) {
          int rg = rowbase + wm * 64 + i * 16 + quad * 4 + r;
          float val = acc[i][j][r] * scl + bv;
          if (f32out) outF[(size_t)rg * ldc + cg] = val;
          else        C[(size_t)rg * ldc + cg] = f2bf(val);
        }
      }
    }
  }
}

// ---------------------------------------------------------------------------
// Flash attention (unchanged from round 6): transpose-free P path, TK=64
// double-buffered, 4 blocks/CU, static softmax, Q pre-scaled by CEXP.
// ---------------------------------------------------------------------------
__global__ __launch_bounds__(256, 4) void attn_fwd(
    const u16* __restrict__ qk, const u16* __restrict__ vT, u16* __restrict__ outp)
{
  __shared__ __align__(16) u16 Ks[2][8][64][8];   // [buf][hd-chunk][key][8]
  __shared__ __align__(16) u16 Vs[2][8][64][8];   // [buf][key-chunk][e][8]

  const int t = threadIdx.x;
  const int lane = t & 63, wave = t >> 6;
  const int quad = lane >> 4, l16 = lane & 15;
  const int bh = blockIdx.x, b = bh >> 4, h = bh & 15;
  const int qtile = blockIdx.y;
  const size_t row0 = (size_t)b * 2048;

  bf16x8 qf[2][2];
  {
    const u16* qp = qk + (row0 + qtile * 128 + wave * 32 + l16) * 2048
                    + h * 64 + quad * 8;
#pragma unroll
    for (int i = 0; i < 2; ++i)
#pragma unroll
      for (int ks = 0; ks < 2; ++ks)
        qf[i][ks] = *(const bf16x8*)(qp + i * 16 * 2048 + ks * 32);
  }

  const u16* Kg[2]; const u16* Vg[2]; unsigned off2[2];
#pragma unroll
  for (int q = 0; q < 2; ++q) {
    int s = q * 256 + t;
    int row = s & 63, c = s >> 6;
    Kg[q] = qk + (row0 + row) * 2048 + (1024 + h * 64 + c * 8);
    Vg[q] = vT + (size_t)(b * 1024 + h * 64 + row) * 2048 + c * 8;
    off2[q] = (unsigned)(s & ~63) * 8;
  }

#pragma unroll
  for (int q = 0; q < 2; ++q) {
    async_copy16(Kg[q], (u16*)Ks + off2[q]);
    async_copy16(Vg[q], (u16*)Vs + off2[q]);
  }

  f32x4 o[2][4] = {};
  float l_r[2] = {0.0f, 0.0f};

  for (int kb = 0; kb < 32; ++kb) {
    const int cur = kb & 1, nxt = cur ^ 1;
    __syncthreads();
    if (kb < 31) {
#pragma unroll
      for (int q = 0; q < 2; ++q) {
        async_copy16(Kg[q] + (size_t)(kb + 1) * 64 * 2048,
                     (u16*)Ks + (unsigned)nxt * 4096 + off2[q]);
        async_copy16(Vg[q] + (kb + 1) * 64,
                     (u16*)Vs + (unsigned)nxt * 4096 + off2[q]);
      }
    }

    f32x4 sc[2][4] = {};
#pragma unroll
    for (int ks = 0; ks < 2; ++ks) {
#pragma unroll
      for (int j = 0; j < 4; ++j) {
        bf16x8 kf = *(const bf16x8*)&Ks[cur][ks * 4 + quad][j * 16 + l16][0];
#pragma unroll
        for (int i = 0; i < 2; ++i)
          sc[i][j] = __builtin_amdgcn_mfma_f32_16x16x32_bf16(kf, qf[i][ks], sc[i][j], 0, 0, 0);
      }
    }

#pragma unroll
    for (int jc = 0; jc < 4; ++jc) {
      bf16x4 vf[4];
#pragma unroll
      for (int et = 0; et < 4; ++et)
        vf[et] = *(const bf16x4*)&Vs[cur][jc * 2 + (quad >> 1)][et * 16 + l16][(quad & 1) * 4];
      bf16x4 pk[2];
#pragma unroll
      for (int i = 0; i < 2; ++i) {
        f32x4 pv;
#pragma unroll
        for (int r = 0; r < 4; ++r) {
          float p = fast_exp2(sc[i][jc][r]);
          pv[r] = p;
          l_r[i] += p;
        }
        pk[i] = __builtin_convertvector(pv, bf16x4);
      }
#pragma unroll
      for (int i = 0; i < 2; ++i)
#pragma unroll
        for (int et = 0; et < 4; ++et)
          o[i][et] = mfma16(pk[i], vf[et], o[i][et]);
    }
  }

#pragma unroll
  for (int i = 0; i < 2; ++i) {
    l_r[i] += __shfl_xor(l_r[i], 16, 64);
    l_r[i] += __shfl_xor(l_r[i], 32, 64);
    l_r[i] = fast_rcp(l_r[i]);
  }
#pragma unroll
  for (int i = 0; i < 2; ++i)
#pragma unroll
    for (int r = 0; r < 4; ++r) {
      float inv = __shfl(l_r[i], ((lane & 48) >> 2) + r, 64);
      int n = qtile * 128 + wave * 32 + i * 16 + quad * 4 + r;
      size_t base = (row0 + n) * 1024 + h * 64;
#pragma unroll
      for (int et = 0; et < 4; ++et)
        outp[base + et * 16 + l16] = f2bf(o[i][et][r] * inv);
    }
}

// ---------------------------------------------------------------------------
// Workspace (u16 elems): qkbuf 16777216 | vT 8388608 | xb/attn 8388608 |
// wqkvb 3145728 | flag. wprojb/bprojb alias vT after attn_fwd.
// ---------------------------------------------------------------------------
extern "C" void kernel_launch(void* const* d_in, const int* in_sizes, int n_in,
                              void* d_out, int out_size, void* d_ws, size_t ws_size,
                              hipStream_t stream) {
  (void)in_sizes; (void)n_in; (void)out_size; (void)ws_size;
  const void* x_in     = d_in[0];
  const void* wqkv_in  = d_in[1];
  const void* wproj_in = d_in[2];
  const void* bproj_in = d_in[3];

  u16* qkbuf  = (u16*)d_ws;
  u16* vT     = qkbuf + 16777216;
  u16* xb     = vT + 8388608;
  u16* wqkvb  = xb + 8388608;
  int* flag   = (int*)(wqkvb + 3145728);
  u16* attn   = xb;
  u16* wprojb = vT;
  u16* bprojb = vT + 1048576;

  detect_mode<<<1, 256, 0, stream>>>((const u32*)wqkv_in, flag);
  convert_in<<<4096, 256, 0, stream>>>(x_in, xb, flag, 8388608);
  convert_in<<<1536, 256, 0, stream>>>(wqkv_in, wqkvb, flag, 3145728);

  gemm_bt<<<dim3(24, 64), 256, 0, stream>>>(xb, wqkvb, qkbuf, vT, nullptr,
                                            nullptr, nullptr, 1024, 2048);
  attn_fwd<<<dim3(64, 16), 256, 0, stream>>>(qkbuf, vT, attn);

  convert_in<<<512, 256, 0, stream>>>(wproj_in, wprojb, flag, 1048576);
  convert_in<<<1, 256, 0, stream>>>(bproj_in, bprojb, flag, 1024);

  gemm_bt<<<dim3(8, 64), 256, 0, stream>>>(attn, wprojb, (u16*)d_out, nullptr,
                                           bprojb, (float*)d_out, flag, 1024, 1024);
}